// Round 3
// baseline (76.436 us; speedup 1.0000x reference)
//
#include <hip/hip_runtime.h>
#include <hip/hip_cooperative_groups.h>
#include <math.h>

namespace cg = cooperative_groups;

#define GN 512
#define GB 2
#define INCH 128
#define GD 64
#define ALPHA 0.2f
#define NEG_INF_F (-9e15f)
#define TI 4   // rows per block

// Fused GAT kernel (cooperative, one launch).
// Phase 1: hidden = x@W (rows blk*4..+3), s1 = a[0:64]·h, s2 = a[64:128]·h.
// grid.sync()
// Phase 2: closed-form logits (validated r1):
//   i < 256 : pre(j) = s12[2i + (j>=256)]
//   i >= 256: pre(j) = s1[2*(j%256)] + s2[2*(j%256)+1]
// masked leaky-relu -> softmax -> out = attn @ hidden + bias.
// Note: flat row blk*4 == b*GN + i0 (b=blk>>7, i0=(blk&127)*4) — same rows both phases.
__global__ __launch_bounds__(512) void k_fused(
        const float* __restrict__ x, const int* __restrict__ adj,
        const float* __restrict__ W, const float* __restrict__ a,
        const float* __restrict__ bias,
        float* __restrict__ hidden, float* __restrict__ s1,
        float* __restrict__ s2, float* __restrict__ s12,
        float* __restrict__ out) {
    const int blk = blockIdx.x;            // 0..255
    const int tid = threadIdx.x;           // 0..511
    const int lane = tid & 63;
    const int w = tid >> 6;                // 0..7
    const int row0 = blk * TI;             // flat row b*GN+n

    __shared__ float Wl[INCH * GD];        // 32 KB
    __shared__ float xs[TI][INCH];         // 2 KB
    __shared__ float hp[TI][2][GD];        // 2 KB k-split partials
    __shared__ int   adjl[TI][GN];         // 8 KB (prefetched pre-sync)
    __shared__ float pl[TI][GN];           // 8 KB softmax weights
    __shared__ float red[8][TI][GD];       // 8 KB PV partials
    __shared__ float invs[TI];

    // ---- Phase 1 staging ----
    const float4* W4 = (const float4*)W;
    float4* Wl4 = (float4*)Wl;
    #pragma unroll
    for (int t = 0; t < 4; ++t) Wl4[tid + t * 512] = W4[tid + t * 512];
    if (tid < TI * INCH / 4)
        ((float4*)xs)[tid] = ((const float4*)(x + (size_t)row0 * INCH))[tid];
    // adj prefetch (independent of phase 1 — hides L2/HBM latency under matmul)
    ((int4*)adjl)[tid] = ((const int4*)(adj + (size_t)row0 * GN))[tid];
    __syncthreads();

    // ---- Phase 1 compute: row r, k-half, column d ----
    {
        const int r = tid >> 7;
        const int half = (tid >> 6) & 1;
        const int d = tid & 63;
        const int k0 = half * 64;
        float h = 0.f;
        #pragma unroll
        for (int k = 0; k < 64; ++k)
            h = fmaf(xs[r][k0 + k], Wl[(k0 + k) * GD + d], h);
        hp[r][half][d] = h;
        __syncthreads();
        if (half == 0) {
            h = hp[r][0][d] + hp[r][1][d];
            hidden[(size_t)(row0 + r) * GD + d] = h;
            float p1 = a[d] * h, p2 = a[GD + d] * h;
            #pragma unroll
            for (int off = 32; off > 0; off >>= 1) {
                p1 += __shfl_xor(p1, off, 64);
                p2 += __shfl_xor(p2, off, 64);
            }
            if (d == 0) {
                s1[row0 + r] = p1; s2[row0 + r] = p2; s12[row0 + r] = p1 + p2;
            }
        }
    }
    __threadfence();
    cg::this_grid().sync();

    // ---- Phase 2 ----
    const int b = blk >> 7;
    const int i0 = (blk & 127) * TI;
    const float* s1b  = s1  + b * GN;
    const float* s2b  = s2  + b * GN;
    const float* s12b = s12 + b * GN;

    if (w < TI) {
        const int i = i0 + w;
        float v[8];
        if (i < 256) {
            float c0 = s12b[2 * i], c1 = s12b[2 * i + 1];
            c0 = c0 >= 0.f ? c0 : ALPHA * c0;
            c1 = c1 >= 0.f ? c1 : ALPHA * c1;
            #pragma unroll
            for (int seg = 0; seg < 8; ++seg) {
                const int j = seg * 64 + lane;
                v[seg] = adjl[w][j] > 0 ? (seg < 4 ? c0 : c1) : NEG_INF_F;
            }
        } else {
            #pragma unroll
            for (int seg = 0; seg < 8; ++seg) {
                const int j = seg * 64 + lane;
                const int m = j & 255;
                float pre = s1b[2 * m] + s2b[2 * m + 1];
                pre = pre >= 0.f ? pre : ALPHA * pre;
                v[seg] = adjl[w][j] > 0 ? pre : NEG_INF_F;
            }
        }
        float mx = v[0];
        #pragma unroll
        for (int seg = 1; seg < 8; ++seg) mx = fmaxf(mx, v[seg]);
        #pragma unroll
        for (int off = 32; off > 0; off >>= 1) mx = fmaxf(mx, __shfl_xor(mx, off, 64));
        float s = 0.f;
        #pragma unroll
        for (int seg = 0; seg < 8; ++seg) {
            const float e = expf(v[seg] - mx);
            pl[w][seg * 64 + lane] = e;
            s += e;
        }
        #pragma unroll
        for (int off = 32; off > 0; off >>= 1) s += __shfl_xor(s, off, 64);
        if (lane == 0) invs[w] = 1.f / s;
    }
    __syncthreads();

    // PV: wave w owns j in [w*64, w*64+64); lane owns column d.
    const float* hb = hidden + (size_t)b * GN * GD;
    const int j0 = w * 64;
    float acc0 = 0.f, acc1 = 0.f, acc2 = 0.f, acc3 = 0.f;
    #pragma unroll 4
    for (int jj = 0; jj < 64; jj += 4) {
        const int j = j0 + jj;
        const float4 q0 = *(const float4*)&pl[0][j];
        const float4 q1 = *(const float4*)&pl[1][j];
        const float4 q2 = *(const float4*)&pl[2][j];
        const float4 q3 = *(const float4*)&pl[3][j];
        float hv;
        hv = hb[(size_t)(j + 0) * GD + lane];
        acc0 = fmaf(q0.x, hv, acc0); acc1 = fmaf(q1.x, hv, acc1);
        acc2 = fmaf(q2.x, hv, acc2); acc3 = fmaf(q3.x, hv, acc3);
        hv = hb[(size_t)(j + 1) * GD + lane];
        acc0 = fmaf(q0.y, hv, acc0); acc1 = fmaf(q1.y, hv, acc1);
        acc2 = fmaf(q2.y, hv, acc2); acc3 = fmaf(q3.y, hv, acc3);
        hv = hb[(size_t)(j + 2) * GD + lane];
        acc0 = fmaf(q0.z, hv, acc0); acc1 = fmaf(q1.z, hv, acc1);
        acc2 = fmaf(q2.z, hv, acc2); acc3 = fmaf(q3.z, hv, acc3);
        hv = hb[(size_t)(j + 3) * GD + lane];
        acc0 = fmaf(q0.w, hv, acc0); acc1 = fmaf(q1.w, hv, acc1);
        acc2 = fmaf(q2.w, hv, acc2); acc3 = fmaf(q3.w, hv, acc3);
    }
    red[w][0][lane] = acc0; red[w][1][lane] = acc1;
    red[w][2][lane] = acc2; red[w][3][lane] = acc3;
    __syncthreads();

    if (tid < TI * GD) {
        const int r = tid >> 6, d = tid & 63;
        float o = 0.f;
        #pragma unroll
        for (int ww = 0; ww < 8; ++ww) o += red[ww][r][d];
        o = o * invs[r] + bias[d];
        out[((size_t)b * GN + i0 + r) * GD + d] = o;
    }
}

extern "C" void kernel_launch(void* const* d_in, const int* in_sizes, int n_in,
                              void* d_out, int out_size, void* d_ws, size_t ws_size,
                              hipStream_t stream) {
    const float* x    = (const float*)d_in[0];
    const int*   adj  = (const int*)d_in[1];
    const float* W    = (const float*)d_in[2];
    const float* a    = (const float*)d_in[3];
    const float* bias = (const float*)d_in[4];
    float* out = (float*)d_out;

    // ws layout (floats): hidden[GB*GN*GD] | s1[GB*GN] | s2[GB*GN] | s12[GB*GN]
    float* ws     = (float*)d_ws;
    float* hidden = ws;
    float* s1f    = hidden + GB * GN * GD;
    float* s2f    = s1f + GB * GN;
    float* s12f   = s2f + GB * GN;

    void* args[] = {(void*)&x, (void*)&adj, (void*)&W, (void*)&a, (void*)&bias,
                    (void*)&hidden, (void*)&s1f, (void*)&s2f, (void*)&s12f,
                    (void*)&out};
    hipLaunchCooperativeKernel((const void*)k_fused, dim3(GB * GN / TI), dim3(512),
                               args, 0, stream);
}

// Round 4
// 21.485 us; speedup vs baseline: 3.5576x; 3.5576x over previous
//
#include <hip/hip_runtime.h>
#include <math.h>

#define GN 512
#define GB 2
#define INCH 128
#define GD 64
#define ALPHA 0.2f
#define NEG_INF_F (-9e15f)
#define TI 4   // attention rows per block

typedef float f32x4 __attribute__((ext_vector_type(4)));
typedef short short8 __attribute__((ext_vector_type(8)));

// dynamic LDS layout (bytes)
#define HB_OFF  0            // hidden bf16 [512][64]            65536
#define ADJ_OFF 65536        // adj int [4][512]                  8192
#define S1_OFF  73728        // s1 f32 [512]                      2048
#define S2_OFF  75776        // s2 f32 [512]                      2048
#define INV_OFF 77824        // invs f32 [4] (+pad to 64B)
#define UN_OFF  77888        // phase1: Wt bf16 swizzled [64][128] (16384)
                             // phase2: pl4 f32[512][4] (8192) + red f32[8][4][64] (8192)
#define LDS_BYTES 94272

__device__ __forceinline__ unsigned f2bf(float f) {  // RNE f32->bf16 bits
    unsigned u = __float_as_uint(f);
    return (u + 0x7FFFu + ((u >> 16) & 1u)) >> 16;
}
__device__ __forceinline__ float bf2f(unsigned short h) {
    return __uint_as_float(((unsigned)h) << 16);
}

// One launch, no inter-block dependency: each block recomputes hidden[b]=x[b]@W
// via bf16 MFMA into LDS, derives s1/s2 from the accumulators, then does
// TI=4 rows of: closed-form logits (validated r1) -> softmax -> PV + bias.
//   i < 256 : pre(j) = s12[2i + (j>=256)]
//   i >= 256: pre(j) = s1[2*(j%256)] + s2[2*(j%256)+1]
__global__ __launch_bounds__(512, 2) void k_fused(
        const float* __restrict__ x, const int* __restrict__ adj,
        const float* __restrict__ W, const float* __restrict__ a,
        const float* __restrict__ bias, float* __restrict__ out) {
    extern __shared__ char smem[];
    const int blk = blockIdx.x;            // 0..255
    const int tid = threadIdx.x;           // 0..511
    const int lane = tid & 63;
    const int w = tid >> 6;                // wave 0..7
    const int lane15 = lane & 15;
    const int kg = lane >> 4;              // 0..3
    const int b = blk >> 7;
    const int i0 = (blk & 127) * TI;       // batch-local row block

    short* hbf  = (short*)(smem + HB_OFF);
    int*   adjl = (int*)(smem + ADJ_OFF);
    float* s1l  = (float*)(smem + S1_OFF);
    float* s2l  = (float*)(smem + S2_OFF);
    float* invs = (float*)(smem + INV_OFF);
    short* wt   = (short*)(smem + UN_OFF);
    float* plf  = (float*)(smem + UN_OFF);            // phase2 alias
    float* red  = (float*)(smem + UN_OFF + 8192);     // phase2 alias

    // ---- stage: Wt (bf16, XOR-swizzled 16B chunks) + adj rows ----
    #pragma unroll
    for (int rep = 0; rep < 4; ++rep) {
        const int idx = tid + rep * 512;           // 0..2047
        const float4 wv = ((const float4*)W)[idx];
        const int k = idx >> 4;                    // 0..127
        const int n0 = (idx & 15) * 4;
        #pragma unroll
        for (int e = 0; e < 4; ++e) {
            const int n = n0 + e;
            const float f = (e == 0) ? wv.x : (e == 1) ? wv.y : (e == 2) ? wv.z : wv.w;
            wt[n * 128 + (((k >> 3) ^ (n & 7)) << 3) + (k & 7)] = (short)f2bf(f);
        }
    }
    ((int4*)adjl)[tid] = ((const int4*)(adj + ((size_t)b * GN + i0) * GN))[tid];
    // a-vector slices for the s-reduction (lane15 owns cols lane15+16*ct)
    float a1v[4], a2v[4];
    #pragma unroll
    for (int ct = 0; ct < 4; ++ct) {
        a1v[ct] = a[ct * 16 + lane15];
        a2v[ct] = a[GD + ct * 16 + lane15];
    }
    __syncthreads();

    // ---- MFMA: wave w computes hidden rows [w*64, w*64+64) ----
    const float* xw = x + ((size_t)b * GN + w * 64) * INCH;
    f32x4 acc[4][4];
    #pragma unroll
    for (int mt = 0; mt < 4; ++mt)
        #pragma unroll
        for (int ct = 0; ct < 4; ++ct)
            acc[mt][ct] = (f32x4)0.f;

    #pragma unroll
    for (int kt = 0; kt < 4; ++kt) {
        short8 av[4];
        #pragma unroll
        for (int mt = 0; mt < 4; ++mt) {       // A: row = l&15, k = (l>>4)*8+e
            const float* p = xw + (mt * 16 + lane15) * INCH + kt * 32 + kg * 8;
            const float4 lo = *((const float4*)p);
            const float4 hi = *((const float4*)(p + 4));
            int4 ai;
            ai.x = f2bf(lo.x) | (f2bf(lo.y) << 16);
            ai.y = f2bf(lo.z) | (f2bf(lo.w) << 16);
            ai.z = f2bf(hi.x) | (f2bf(hi.y) << 16);
            ai.w = f2bf(hi.z) | (f2bf(hi.w) << 16);
            av[mt] = __builtin_bit_cast(short8, ai);
        }
        #pragma unroll
        for (int ct = 0; ct < 4; ++ct) {       // B: col = l&15, k = (l>>4)*8+e
            const int n = ct * 16 + lane15;
            const int c = kt * 4 + kg;
            const short8 bv = *((const short8*)(smem + UN_OFF + n * 256 + ((c ^ (n & 7)) << 4)));
            #pragma unroll
            for (int mt = 0; mt < 4; ++mt)
                acc[mt][ct] = __builtin_amdgcn_mfma_f32_16x16x32_bf16(
                                  av[mt], bv, acc[mt][ct], 0, 0, 0);
        }
    }

    // ---- s1/s2 from accumulators (C/D: col=l&15, row=(l>>4)*4+reg) ----
    #pragma unroll
    for (int mt = 0; mt < 4; ++mt) {
        #pragma unroll
        for (int r = 0; r < 4; ++r) {
            float t1 = acc[mt][0][r] * a1v[0] + acc[mt][1][r] * a1v[1]
                     + acc[mt][2][r] * a1v[2] + acc[mt][3][r] * a1v[3];
            float t2 = acc[mt][0][r] * a2v[0] + acc[mt][1][r] * a2v[1]
                     + acc[mt][2][r] * a2v[2] + acc[mt][3][r] * a2v[3];
            #pragma unroll
            for (int off = 1; off < 16; off <<= 1) {
                t1 += __shfl_xor(t1, off, 64);
                t2 += __shfl_xor(t2, off, 64);
            }
            const int row = w * 64 + mt * 16 + kg * 4 + r;
            if (lane15 == 0) { s1l[row] = t1; s2l[row] = t2; }
        }
    }
    // ---- writeback hidden (bf16) ----
    #pragma unroll
    for (int mt = 0; mt < 4; ++mt)
        #pragma unroll
        for (int ct = 0; ct < 4; ++ct)
            #pragma unroll
            for (int r = 0; r < 4; ++r) {
                const int row = w * 64 + mt * 16 + kg * 4 + r;
                hbf[row * GD + ct * 16 + lane15] = (short)f2bf(acc[mt][ct][r]);
            }
    __syncthreads();   // hidden + s visible; Wt region free for pl4/red

    // ---- softmax for rows i0..i0+3 (waves 0..3) ----
    if (w < TI) {
        const int i = i0 + w;
        const int* adjw = adjl + w * GN;
        float v[8];
        if (i < 256) {
            float c0 = s1l[2 * i] + s2l[2 * i];
            float c1 = s1l[2 * i + 1] + s2l[2 * i + 1];
            c0 = c0 >= 0.f ? c0 : ALPHA * c0;
            c1 = c1 >= 0.f ? c1 : ALPHA * c1;
            #pragma unroll
            for (int seg = 0; seg < 8; ++seg)
                v[seg] = adjw[seg * 64 + lane] > 0 ? (seg < 4 ? c0 : c1) : NEG_INF_F;
        } else {
            #pragma unroll
            for (int seg = 0; seg < 8; ++seg) {
                const int m = (seg * 64 + lane) & 255;
                float pre = s1l[2 * m] + s2l[2 * m + 1];
                pre = pre >= 0.f ? pre : ALPHA * pre;
                v[seg] = adjw[seg * 64 + lane] > 0 ? pre : NEG_INF_F;
            }
        }
        float mx = v[0];
        #pragma unroll
        for (int seg = 1; seg < 8; ++seg) mx = fmaxf(mx, v[seg]);
        #pragma unroll
        for (int off = 32; off > 0; off >>= 1) mx = fmaxf(mx, __shfl_xor(mx, off, 64));
        float s = 0.f;
        #pragma unroll
        for (int seg = 0; seg < 8; ++seg) {
            const float e = expf(v[seg] - mx);
            plf[(seg * 64 + lane) * 4 + w] = e;
            s += e;
        }
        #pragma unroll
        for (int off = 32; off > 0; off >>= 1) s += __shfl_xor(s, off, 64);
        if (lane == 0) invs[w] = 1.f / s;
    }
    __syncthreads();

    // ---- PV: wave w owns j in [w*64, w*64+64); lane owns column d ----
    const int j0 = w * 64;
    float o0 = 0.f, o1 = 0.f, o2 = 0.f, o3 = 0.f;
    #pragma unroll 4
    for (int jj = 0; jj < 64; ++jj) {
        const int j = j0 + jj;
        const float4 q = *((const float4*)(plf + j * 4));  // uniform -> broadcast
        const float h = bf2f((unsigned short)hbf[j * GD + lane]);
        o0 = fmaf(q.x, h, o0); o1 = fmaf(q.y, h, o1);
        o2 = fmaf(q.z, h, o2); o3 = fmaf(q.w, h, o3);
    }
    red[(w * 4 + 0) * 64 + lane] = o0;
    red[(w * 4 + 1) * 64 + lane] = o1;
    red[(w * 4 + 2) * 64 + lane] = o2;
    red[(w * 4 + 3) * 64 + lane] = o3;
    __syncthreads();

    if (tid < TI * GD) {
        const int r = tid >> 6, d = tid & 63;
        float o = 0.f;
        #pragma unroll
        for (int ww = 0; ww < 8; ++ww) o += red[(ww * 4 + r) * 64 + d];
        o = o * invs[r] + bias[d];
        out[((size_t)b * GN + i0 + r) * GD + d] = o;
    }
}

extern "C" void kernel_launch(void* const* d_in, const int* in_sizes, int n_in,
                              void* d_out, int out_size, void* d_ws, size_t ws_size,
                              hipStream_t stream) {
    const float* x    = (const float*)d_in[0];
    const int*   adj  = (const int*)d_in[1];
    const float* W    = (const float*)d_in[2];
    const float* a    = (const float*)d_in[3];
    const float* bias = (const float*)d_in[4];
    float* out = (float*)d_out;

    (void)hipFuncSetAttribute((const void*)k_fused,
                              hipFuncAttributeMaxDynamicSharedMemorySize, LDS_BYTES);
    k_fused<<<GB * GN / TI, 512, LDS_BYTES, stream>>>(x, adj, W, a, bias, out);
}

// Round 6
// 18.189 us; speedup vs baseline: 4.2023x; 1.1812x over previous
//
#include <hip/hip_runtime.h>
#include <math.h>

#define GN 512
#define GB 2
#define INCH 128
#define GD 64
#define ALPHA 0.2f
#define NEG_INF_F (-9e15f)
#define TI 4   // attention rows per block

typedef float f32x4 __attribute__((ext_vector_type(4)));
typedef short short8 __attribute__((ext_vector_type(8)));

// LDS layout (bytes). All cross-wave handoffs are protected by __syncthreads.
#define XT0_OFF 0        // x-chunk buf A: bf16 [128 rows][128 k], slot-swizzled, 32 KB
#define XT1_OFF 32768    // x-chunk buf B, 32 KB
#define HB_OFF  65536    // hidden bf16 [512][64], kg-col-swizzled, 64 KB
#define ADJ_OFF 131072   // adj int [4][512], 8 KB
#define S1_OFF  139264   // s1 f32 [512]
#define S2_OFF  141312   // s2 f32 [512]
#define INV_OFF 143360   // invs f32 [4] (+pad)
#define WT_OFF  143424   // phase1: Wt bf16 swizzled, 16 KB
#define PL_OFF  143424   // phase2 alias: plf f32 [512][4], 8 KB
#define RED_OFF 151616   // phase2 alias: red f32 [8][4][64], 8 KB
#define LDS_BYTES 159808

__device__ __forceinline__ unsigned f2bf(float f) {  // RNE f32->bf16 bits
    unsigned u = __float_as_uint(f);
    return (u + 0x7FFFu + ((u >> 16) & 1u)) >> 16;
}
__device__ __forceinline__ float bf2f(unsigned short h) {
    return __uint_as_float(((unsigned)h) << 16);
}

// One launch. Each block recomputes hidden[b] = x[b]@W with bf16 MFMA:
// x staged chunk-by-chunk (128 rows) via registers -> bf16 -> LDS, double
// buffered with plain barriers (loads for chunk c+1 issue before compute of
// chunk c -> latency hidden; no inline asm, no counted vmcnt). Then s1/s2 from
// accumulators, and TI=4 rows of closed-form logits (validated r1) -> softmax
// -> PV + bias:
//   i < 256 : pre(j) = s12[2i + (j>=256)]
//   i >= 256: pre(j) = s1[2*(j%256)] + s2[2*(j%256)+1]
__global__ __launch_bounds__(512, 2) void k_fused(
        const float* __restrict__ x, const int* __restrict__ adj,
        const float* __restrict__ W, const float* __restrict__ a,
        const float* __restrict__ bias, float* __restrict__ out) {
    extern __shared__ char smem[];
    const int blk = blockIdx.x;            // 0..255
    const int tid = threadIdx.x;           // 0..511
    const int lane = tid & 63;
    const int w = tid >> 6;                // wave 0..7
    const int lane15 = lane & 15;
    const int kg = lane >> 4;              // 0..3
    const int b = blk >> 7;
    const int i0 = (blk & 127) * TI;

    short* hbf  = (short*)(smem + HB_OFF);
    int*   adjl = (int*)(smem + ADJ_OFF);
    float* s1l  = (float*)(smem + S1_OFF);
    float* s2l  = (float*)(smem + S2_OFF);
    float* invs = (float*)(smem + INV_OFF);
    short* wt   = (short*)(smem + WT_OFF);
    float* plf  = (float*)(smem + PL_OFF);
    float* red  = (float*)(smem + RED_OFF);

    const float* xb = x + (size_t)b * GN * INCH;

    // ---- prologue staging: Wt + adj + chunk0 ----
    #pragma unroll
    for (int rep = 0; rep < 4; ++rep) {
        const int idx = tid + rep * 512;               // 0..2047 float4s of W
        const float4 wv = ((const float4*)W)[idx];
        const int k = idx >> 4;                        // 0..127
        const int n0 = (idx & 15) * 4;
        #pragma unroll
        for (int e = 0; e < 4; ++e) {
            const int n = n0 + e;
            const float f = (e == 0) ? wv.x : (e == 1) ? wv.y : (e == 2) ? wv.z : wv.w;
            wt[n * 128 + (((k >> 3) ^ ((n >> 1) & 7)) << 3) + (k & 7)] = (short)f2bf(f);
        }
    }
    ((int4*)adjl)[tid] = ((const int4*)(adj + ((size_t)b * GN + i0) * GN))[tid];
    float a1v[4], a2v[4];
    #pragma unroll
    for (int ct = 0; ct < 4; ++ct) {
        a1v[ct] = a[ct * 16 + lane15];
        a2v[ct] = a[GD + ct * 16 + lane15];
    }
    // chunk0: coalesced f32 loads -> bf16 pack -> swizzled LDS write
    float4 g[8];
    #pragma unroll
    for (int it = 0; it < 8; ++it)
        g[it] = ((const float4*)xb)[tid + it * 512];
    #pragma unroll
    for (int it = 0; it < 8; ++it) {
        const int f = tid + it * 512;                  // float4 index in chunk
        const int row = f >> 5;                        // 0..127
        const int c16 = (f & 31) >> 1;                 // 16B bf16 slot 0..15
        const int half = f & 1;
        int2 pk;
        pk.x = f2bf(g[it].x) | (f2bf(g[it].y) << 16);
        pk.y = f2bf(g[it].z) | (f2bf(g[it].w) << 16);
        *(int2*)(smem + XT0_OFF + row * 256 +
                 ((c16 ^ ((row & 7) << 1)) << 4) + half * 8) = pk;
    }
    __syncthreads();

    // ---- preload all 16 B-fragments into registers (wt region then dead) ----
    short8 bfr[4][4];
    #pragma unroll
    for (int kt = 0; kt < 4; ++kt)
        #pragma unroll
        for (int ct = 0; ct < 4; ++ct) {
            const int n = ct * 16 + lane15;
            const int c = kt * 4 + kg;
            bfr[kt][ct] = *((const short8*)((char*)wt + n * 256 +
                                            ((c ^ ((n >> 1) & 7)) << 4)));
        }

    // ---- chunk loop: 4 x (128 rows), dbuf with plain barriers ----
    #pragma unroll
    for (int c = 0; c < 4; ++c) {
        const unsigned cur = (c & 1) ? XT1_OFF : XT0_OFF;
        const unsigned nxt = (c & 1) ? XT0_OFF : XT1_OFF;
        if (c < 3) {       // issue next-chunk loads early (latency under compute)
            const float4* xc = (const float4*)(xb + (size_t)(c + 1) * 128 * INCH);
            #pragma unroll
            for (int it = 0; it < 8; ++it) g[it] = xc[tid + it * 512];
        }
        // compute chunk c: wave w owns rows w*16..w*16+15 of the chunk
        const int mrow = w * 16 + lane15;
        short8 av[4];
        #pragma unroll
        for (int kt = 0; kt < 4; ++kt)
            av[kt] = *((const short8*)(smem + cur + mrow * 256 +
                       (((kt * 4 + kg) ^ ((lane15 & 7) << 1)) << 4)));
        f32x4 acc[4];
        #pragma unroll
        for (int ct = 0; ct < 4; ++ct) acc[ct] = (f32x4)0.f;
        #pragma unroll
        for (int kt = 0; kt < 4; ++kt)
            #pragma unroll
            for (int ct = 0; ct < 4; ++ct)
                acc[ct] = __builtin_amdgcn_mfma_f32_16x16x32_bf16(
                              av[kt], bfr[kt][ct], acc[ct], 0, 0, 0);
        // s1/s2 (C/D: col = lane&15, row = kg*4 + r)
        #pragma unroll
        for (int r = 0; r < 4; ++r) {
            float t1 = acc[0][r] * a1v[0] + acc[1][r] * a1v[1]
                     + acc[2][r] * a1v[2] + acc[3][r] * a1v[3];
            float t2 = acc[0][r] * a2v[0] + acc[1][r] * a2v[1]
                     + acc[2][r] * a2v[2] + acc[3][r] * a2v[3];
            #pragma unroll
            for (int off = 1; off < 16; off <<= 1) {
                t1 += __shfl_xor(t1, off, 64);
                t2 += __shfl_xor(t2, off, 64);
            }
            const int grow = c * 128 + w * 16 + kg * 4 + r;
            if (lane15 == 0) { s1l[grow] = t1; s2l[grow] = t2; }
        }
        // hidden writeback (bf16, kg-swizzled cols -> conflict-free, r5-validated)
        #pragma unroll
        for (int ct = 0; ct < 4; ++ct)
            #pragma unroll
            for (int r = 0; r < 4; ++r) {
                const int grow = c * 128 + w * 16 + kg * 4 + r;
                const int col = (ct * 16 + lane15) ^ (kg << 4);
                hbf[grow * GD + col] = (short)f2bf(acc[ct][r]);
            }
        if (c < 3) {       // stage next chunk (target buffer idle since last barrier)
            #pragma unroll
            for (int it = 0; it < 8; ++it) {
                const int f = tid + it * 512;
                const int row = f >> 5;
                const int c16 = (f & 31) >> 1;
                const int half = f & 1;
                int2 pk;
                pk.x = f2bf(g[it].x) | (f2bf(g[it].y) << 16);
                pk.y = f2bf(g[it].z) | (f2bf(g[it].w) << 16);
                *(int2*)(smem + nxt + row * 256 +
                         ((c16 ^ ((row & 7) << 1)) << 4) + half * 8) = pk;
            }
        }
        __syncthreads();
    }

    // ---- softmax for rows i0..i0+3 (waves 0..3) ----
    if (w < TI) {
        const int i = i0 + w;
        const int* adjw = adjl + w * GN;
        float v[8];
        if (i < 256) {
            float c0 = s1l[2 * i] + s2l[2 * i];
            float c1 = s1l[2 * i + 1] + s2l[2 * i + 1];
            c0 = c0 >= 0.f ? c0 : ALPHA * c0;
            c1 = c1 >= 0.f ? c1 : ALPHA * c1;
            #pragma unroll
            for (int seg = 0; seg < 8; ++seg)
                v[seg] = adjw[seg * 64 + lane] > 0 ? (seg < 4 ? c0 : c1) : NEG_INF_F;
        } else {
            #pragma unroll
            for (int seg = 0; seg < 8; ++seg) {
                const int m = (seg * 64 + lane) & 255;
                float pre = s1l[2 * m] + s2l[2 * m + 1];
                pre = pre >= 0.f ? pre : ALPHA * pre;
                v[seg] = adjw[seg * 64 + lane] > 0 ? pre : NEG_INF_F;
            }
        }
        float mx = v[0];
        #pragma unroll
        for (int seg = 1; seg < 8; ++seg) mx = fmaxf(mx, v[seg]);
        #pragma unroll
        for (int off = 32; off > 0; off >>= 1) mx = fmaxf(mx, __shfl_xor(mx, off, 64));
        float s = 0.f;
        #pragma unroll
        for (int seg = 0; seg < 8; ++seg) {
            const float e = __expf(v[seg] - mx);
            plf[(seg * 64 + lane) * 4 + w] = e;
            s += e;
        }
        #pragma unroll
        for (int off = 32; off > 0; off >>= 1) s += __shfl_xor(s, off, 64);
        if (lane == 0) invs[w] = 1.f / s;
    }
    __syncthreads();

    // ---- PV: wave w owns j in [w*64, w*64+64); lane owns column d ----
    const int j0 = w * 64;
    float o0 = 0.f, o1 = 0.f, o2 = 0.f, o3 = 0.f;
    #pragma unroll 8
    for (int jj = 0; jj < 64; ++jj) {
        const int j = j0 + jj;
        const float4 q = *((const float4*)(plf + j * 4));  // uniform -> broadcast
        const float h = bf2f((unsigned short)hbf[j * GD + (lane ^ (((j >> 2) & 3) << 4))]);
        o0 = fmaf(q.x, h, o0); o1 = fmaf(q.y, h, o1);
        o2 = fmaf(q.z, h, o2); o3 = fmaf(q.w, h, o3);
    }
    red[(w * 4 + 0) * 64 + lane] = o0;
    red[(w * 4 + 1) * 64 + lane] = o1;
    red[(w * 4 + 2) * 64 + lane] = o2;
    red[(w * 4 + 3) * 64 + lane] = o3;
    __syncthreads();

    if (tid < TI * GD) {
        const int r = tid >> 6, d = tid & 63;
        float o = 0.f;
        #pragma unroll
        for (int ww = 0; ww < 8; ++ww) o += red[(ww * 4 + r) * 64 + d];
        o = o * invs[r] + bias[d];
        out[((size_t)b * GN + i0 + r) * GD + d] = o;
    }
}

extern "C" void kernel_launch(void* const* d_in, const int* in_sizes, int n_in,
                              void* d_out, int out_size, void* d_ws, size_t ws_size,
                              hipStream_t stream) {
    const float* x    = (const float*)d_in[0];
    const int*   adj  = (const int*)d_in[1];
    const float* W    = (const float*)d_in[2];
    const float* a    = (const float*)d_in[3];
    const float* bias = (const float*)d_in[4];
    float* out = (float*)d_out;

    (void)hipFuncSetAttribute((const void*)k_fused,
                              hipFuncAttributeMaxDynamicSharedMemorySize, LDS_BYTES);
    k_fused<<<GB * GN / TI, 512, LDS_BYTES, stream>>>(x, adj, W, a, bias, out);
}

// Round 7
// 15.363 us; speedup vs baseline: 4.9753x; 1.1840x over previous
//
#include <hip/hip_runtime.h>
#include <math.h>

#define GN 512
#define GB 2
#define INCH 128
#define GD 64
#define ALPHA 0.2f
#define NEG_INF_F (-9e15f)
#define TI 4   // attention rows per k_attn block

__device__ __forceinline__ unsigned f2bf(float f) {  // RNE f32->bf16 bits
    unsigned u = __float_as_uint(f);
    return (u + 0x7FFFu + ((u >> 16) & 1u)) >> 16;
}
__device__ __forceinline__ float bf2f(unsigned short h) {
    return __uint_as_float(((unsigned)h) << 16);
}

// K1: hidden(bf16) = x @ W, s1 = a[0:64]·h, s2 = a[64:128]·h.
// 256 blocks x 256 threads; 4 rows/block; W staged in LDS (validated r2).
__global__ __launch_bounds__(256) void k_hidden(
        const float* __restrict__ x, const float* __restrict__ W,
        const float* __restrict__ a,
        unsigned short* __restrict__ hbf, float* __restrict__ s1,
        float* __restrict__ s2) {
    const int row0 = blockIdx.x * 4;       // flat row b*GN+n, 0..1023
    const int tid = threadIdx.x;
    __shared__ float Wl[INCH * GD];        // 32 KB
    __shared__ float xs[4][INCH];          // 2 KB

    const float4* W4 = (const float4*)W;
    float4* Wl4 = (float4*)Wl;
    #pragma unroll
    for (int t = 0; t < 8; ++t) Wl4[tid + t * 256] = W4[tid + t * 256];
    if (tid < 4 * INCH / 4)
        ((float4*)xs)[tid] = ((const float4*)(x + (size_t)row0 * INCH))[tid];
    __syncthreads();

    const int r = tid >> 6, d = tid & 63;
    float h = 0.f;
    #pragma unroll
    for (int k = 0; k < INCH; ++k) h = fmaf(xs[r][k], Wl[k * GD + d], h);
    hbf[(size_t)(row0 + r) * GD + d] = (unsigned short)f2bf(h);

    float p1 = a[d] * h, p2 = a[GD + d] * h;
    #pragma unroll
    for (int off = 32; off > 0; off >>= 1) {
        p1 += __shfl_xor(p1, off, 64);
        p2 += __shfl_xor(p2, off, 64);
    }
    if (d == 0) { s1[row0 + r] = p1; s2[row0 + r] = p2; }
}

// K2: per (b,i): closed-form logits (validated r1-r6) -> masked leaky-relu ->
// softmax -> out = attn @ hidden(bf16) + bias.
//   i < 256 : pre(j) = (s1+s2)[2i + (j>=256)]
//   i >= 256: pre(j) = s1[2*(j%256)] + s2[2*(j%256)+1]   (period 4 in seg)
// 256 blocks x 512 threads; TI=4 rows/block. adj + hbf read straight from
// global (L2-resident; no LDS staging per common-mistake #7).
__global__ __launch_bounds__(512) void k_attn(
        const int* __restrict__ adj, const unsigned short* __restrict__ hbf,
        const float* __restrict__ s1, const float* __restrict__ s2,
        const float* __restrict__ bias, float* __restrict__ out) {
    const int blk = blockIdx.x;
    const int b = blk >> 7;
    const int i0 = (blk & 127) * TI;
    const int tid = threadIdx.x;
    const int lane = tid & 63;
    const int w = tid >> 6;                // 0..7

    __shared__ float plf[GN * TI];         // 8 KB, transposed: plf[j*4+row]
    __shared__ float red[8 * TI * GD];     // 8 KB
    __shared__ float invs[TI];

    const float* s1b = s1 + b * GN;
    const float* s2b = s2 + b * GN;

    if (w < TI) {
        const int i = i0 + w;
        const int* adjw = adj + ((size_t)b * GN + i) * GN;
        float pre4[4];
        if (i < 256) {
            float c0 = s1b[2 * i] + s2b[2 * i];
            float c1 = s1b[2 * i + 1] + s2b[2 * i + 1];
            c0 = c0 >= 0.f ? c0 : ALPHA * c0;
            c1 = c1 >= 0.f ? c1 : ALPHA * c1;
            pre4[0] = pre4[1] = pre4[2] = pre4[3] = c0;  // segs 0-3 use c0
            // segs 4-7 use c1: handled below via sel
            float v[8];
            #pragma unroll
            for (int seg = 0; seg < 8; ++seg)
                v[seg] = adjw[seg * 64 + lane] > 0 ? (seg < 4 ? c0 : c1) : NEG_INF_F;
            float mx = v[0];
            #pragma unroll
            for (int seg = 1; seg < 8; ++seg) mx = fmaxf(mx, v[seg]);
            #pragma unroll
            for (int off = 32; off > 0; off >>= 1) mx = fmaxf(mx, __shfl_xor(mx, off, 64));
            float s = 0.f;
            #pragma unroll
            for (int seg = 0; seg < 8; ++seg) {
                const float e = __expf(v[seg] - mx);
                plf[(seg * 64 + lane) * TI + w] = e;
                s += e;
            }
            #pragma unroll
            for (int off = 32; off > 0; off >>= 1) s += __shfl_xor(s, off, 64);
            if (lane == 0) invs[w] = 1.f / s;
        } else {
            #pragma unroll
            for (int sg = 0; sg < 4; ++sg) {         // m has period 4 in seg
                const int m = (sg * 64 + lane) & 255;
                float pre = s1b[2 * m] + s2b[2 * m + 1];
                pre4[sg] = pre >= 0.f ? pre : ALPHA * pre;
            }
            float v[8];
            #pragma unroll
            for (int seg = 0; seg < 8; ++seg)
                v[seg] = adjw[seg * 64 + lane] > 0 ? pre4[seg & 3] : NEG_INF_F;
            float mx = v[0];
            #pragma unroll
            for (int seg = 1; seg < 8; ++seg) mx = fmaxf(mx, v[seg]);
            #pragma unroll
            for (int off = 32; off > 0; off >>= 1) mx = fmaxf(mx, __shfl_xor(mx, off, 64));
            float s = 0.f;
            #pragma unroll
            for (int seg = 0; seg < 8; ++seg) {
                const float e = __expf(v[seg] - mx);
                plf[(seg * 64 + lane) * TI + w] = e;
                s += e;
            }
            #pragma unroll
            for (int off = 32; off > 0; off >>= 1) s += __shfl_xor(s, off, 64);
            if (lane == 0) invs[w] = 1.f / s;
        }
    }
    __syncthreads();

    // PV: wave w owns j in [w*64, w*64+64); lane owns column d = lane.
    // hbf read from global: 2B/lane x 64 lanes = one 128B line pair per j.
    const unsigned short* hbg = hbf + (size_t)b * GN * GD;
    const int j0 = w * 64;
    float o0 = 0.f, o1 = 0.f, o2 = 0.f, o3 = 0.f;
    #pragma unroll 8
    for (int jj = 0; jj < 64; ++jj) {
        const int j = j0 + jj;
        const float4 q = *((const float4*)(plf + j * TI));  // uniform -> broadcast
        const float h = bf2f(hbg[j * GD + lane]);
        o0 = fmaf(q.x, h, o0); o1 = fmaf(q.y, h, o1);
        o2 = fmaf(q.z, h, o2); o3 = fmaf(q.w, h, o3);
    }
    red[(w * TI + 0) * GD + lane] = o0;
    red[(w * TI + 1) * GD + lane] = o1;
    red[(w * TI + 2) * GD + lane] = o2;
    red[(w * TI + 3) * GD + lane] = o3;
    __syncthreads();

    if (tid < TI * GD) {
        const int r = tid >> 6, d = tid & 63;
        float o = 0.f;
        #pragma unroll
        for (int ww = 0; ww < 8; ++ww) o += red[(ww * TI + r) * GD + d];
        o = o * invs[r] + bias[d];
        out[((size_t)b * GN + i0 + r) * GD + d] = o;
    }
}

extern "C" void kernel_launch(void* const* d_in, const int* in_sizes, int n_in,
                              void* d_out, int out_size, void* d_ws, size_t ws_size,
                              hipStream_t stream) {
    const float* x    = (const float*)d_in[0];
    const int*   adj  = (const int*)d_in[1];
    const float* W    = (const float*)d_in[2];
    const float* a    = (const float*)d_in[3];
    const float* bias = (const float*)d_in[4];
    float* out = (float*)d_out;

    // ws layout: hbf ushort[GB*GN*GD] | s1 f32[GB*GN] | s2 f32[GB*GN]
    unsigned short* hbf = (unsigned short*)d_ws;
    float* s1f = (float*)((char*)d_ws + GB * GN * GD * sizeof(unsigned short));
    float* s2f = s1f + GB * GN;

    k_hidden<<<GB * GN / 4, 256, 0, stream>>>(x, W, a, hbf, s1f, s2f);
    k_attn<<<GB * GN / TI, 512, 0, stream>>>(adj, hbf, s1f, s2f, bias, out);
}

// Round 8
// 14.359 us; speedup vs baseline: 5.3232x; 1.0699x over previous
//
#include <hip/hip_runtime.h>
#include <math.h>

#define GN 512
#define GB 2
#define INCH 128
#define GD 64
#define ALPHA 0.2f
#define NEG_INF_F (-9e15f)
#define TI 4   // attention rows per k_attn block

__device__ __forceinline__ unsigned f2bf(float f) {  // RNE f32->bf16 bits
    unsigned u = __float_as_uint(f);
    return (u + 0x7FFFu + ((u >> 16) & 1u)) >> 16;
}
__device__ __forceinline__ float bf2f(unsigned short h) {
    return __uint_as_float(((unsigned)h) << 16);
}

// K1: hidden(bf16) = x @ W, s1 = a[0:64]·h, s2 = a[64:128]·h.
// 256 blocks x 256 threads; 4 rows/block; W staged in LDS (validated r2/r7).
__global__ __launch_bounds__(256) void k_hidden(
        const float* __restrict__ x, const float* __restrict__ W,
        const float* __restrict__ a,
        unsigned short* __restrict__ hbf, float* __restrict__ s1,
        float* __restrict__ s2) {
    const int row0 = blockIdx.x * 4;       // flat row b*GN+n, 0..1023
    const int tid = threadIdx.x;
    __shared__ float Wl[INCH * GD];        // 32 KB
    __shared__ float xs[4][INCH];          // 2 KB

    const float4* W4 = (const float4*)W;
    float4* Wl4 = (float4*)Wl;
    #pragma unroll
    for (int t = 0; t < 8; ++t) Wl4[tid + t * 256] = W4[tid + t * 256];
    if (tid < 4 * INCH / 4)
        ((float4*)xs)[tid] = ((const float4*)(x + (size_t)row0 * INCH))[tid];
    __syncthreads();

    const int r = tid >> 6, d = tid & 63;
    float h = 0.f;
    #pragma unroll
    for (int k = 0; k < INCH; ++k) h = fmaf(xs[r][k], Wl[k * GD + d], h);
    hbf[(size_t)(row0 + r) * GD + d] = (unsigned short)f2bf(h);

    float p1 = a[d] * h, p2 = a[GD + d] * h;
    #pragma unroll
    for (int off = 32; off > 0; off >>= 1) {
        p1 += __shfl_xor(p1, off, 64);
        p2 += __shfl_xor(p2, off, 64);
    }
    if (d == 0) { s1[row0 + r] = p1; s2[row0 + r] = p2; }
}

// K2: per (b,i): closed-form logits (validated r1-r7) -> masked leaky-relu ->
// softmax (normalized weights in LDS) -> out = attn @ hidden(bf16) + bias.
//   i < 256 : pre(j) = (s1+s2)[2i + (j>=256)]
//   i >= 256: pre(j) = s1[2*(j%256)] + s2[2*(j%256)+1]   (period 4 in seg)
// 256 blocks x 512 threads; TI=4 rows/block. PV hbf loads preissued into
// registers BEFORE the softmax barrier (latency hides under softmax; T14).
// PV: lane owns d-pair (2*ld, 2*ld+1); half-wave lh handles j parity; one
// shfl_xor(32) merges the halves at the end.
__global__ __launch_bounds__(512) void k_attn(
        const int* __restrict__ adj, const unsigned short* __restrict__ hbf,
        const float* __restrict__ s1, const float* __restrict__ s2,
        const float* __restrict__ bias, float* __restrict__ out) {
    const int blk = blockIdx.x;
    const int b = blk >> 7;
    const int i0 = (blk & 127) * TI;
    const int tid = threadIdx.x;
    const int lane = tid & 63;
    const int w = tid >> 6;                // 0..7
    const int ld = lane & 31;              // d-pair index
    const int lh = lane >> 5;              // j parity

    __shared__ float plf[GN * TI];         // 8 KB, transposed+normalized: plf[j*4+row]
    __shared__ float red[8 * TI * GD];     // 8 KB

    // ---- preissue PV loads (independent of softmax) ----
    const unsigned short* hbg = hbf + (size_t)b * GN * GD;
    const int j0 = w * 64;
    unsigned int hv[32];                   // ushort2 h[j0+2*jj+lh][2*ld..2*ld+1]
    #pragma unroll
    for (int jj = 0; jj < 32; ++jj)
        hv[jj] = *((const unsigned int*)(hbg + (size_t)(j0 + 2 * jj + lh) * GD + 2 * ld));

    const float* s1b = s1 + b * GN;
    const float* s2b = s2 + b * GN;

    if (w < TI) {
        const int i = i0 + w;
        const int* adjw = adj + ((size_t)b * GN + i) * GN;
        float v[8];
        if (i < 256) {
            float c0 = s1b[2 * i] + s2b[2 * i];
            float c1 = s1b[2 * i + 1] + s2b[2 * i + 1];
            c0 = c0 >= 0.f ? c0 : ALPHA * c0;
            c1 = c1 >= 0.f ? c1 : ALPHA * c1;
            #pragma unroll
            for (int seg = 0; seg < 8; ++seg)
                v[seg] = adjw[seg * 64 + lane] > 0 ? (seg < 4 ? c0 : c1) : NEG_INF_F;
        } else {
            float pre4[4];
            #pragma unroll
            for (int sg = 0; sg < 4; ++sg) {         // m has period 4 in seg
                const int m = (sg * 64 + lane) & 255;
                float pre = s1b[2 * m] + s2b[2 * m + 1];
                pre4[sg] = pre >= 0.f ? pre : ALPHA * pre;
            }
            #pragma unroll
            for (int seg = 0; seg < 8; ++seg)
                v[seg] = adjw[seg * 64 + lane] > 0 ? pre4[seg & 3] : NEG_INF_F;
        }
        float mx = v[0];
        #pragma unroll
        for (int seg = 1; seg < 8; ++seg) mx = fmaxf(mx, v[seg]);
        #pragma unroll
        for (int off = 32; off > 0; off >>= 1) mx = fmaxf(mx, __shfl_xor(mx, off, 64));
        float e[8], s = 0.f;
        #pragma unroll
        for (int seg = 0; seg < 8; ++seg) {
            e[seg] = __expf(v[seg] - mx);
            s += e[seg];
        }
        #pragma unroll
        for (int off = 32; off > 0; off >>= 1) s += __shfl_xor(s, off, 64);
        const float inv = 1.f / s;
        #pragma unroll
        for (int seg = 0; seg < 8; ++seg)
            plf[(seg * 64 + lane) * TI + w] = e[seg] * inv;   // pre-normalized
    }
    __syncthreads();

    // ---- PV (pure LDS+VALU; loads already in hv) ----
    float a00 = 0.f, a01 = 0.f, a10 = 0.f, a11 = 0.f;
    float a20 = 0.f, a21 = 0.f, a30 = 0.f, a31 = 0.f;
    #pragma unroll 8
    for (int jj = 0; jj < 32; ++jj) {
        const int j = j0 + 2 * jj + lh;
        const float4 q = *((const float4*)(plf + j * TI));  // 2-addr broadcast
        const float h0 = bf2f((unsigned short)(hv[jj] & 0xFFFFu));
        const float h1 = bf2f((unsigned short)(hv[jj] >> 16));
        a00 = fmaf(q.x, h0, a00); a01 = fmaf(q.x, h1, a01);
        a10 = fmaf(q.y, h0, a10); a11 = fmaf(q.y, h1, a11);
        a20 = fmaf(q.z, h0, a20); a21 = fmaf(q.z, h1, a21);
        a30 = fmaf(q.w, h0, a30); a31 = fmaf(q.w, h1, a31);
    }
    // merge j-parity halves (lane <-> lane+32 hold same d-pair)
    a00 += __shfl_xor(a00, 32, 64); a01 += __shfl_xor(a01, 32, 64);
    a10 += __shfl_xor(a10, 32, 64); a11 += __shfl_xor(a11, 32, 64);
    a20 += __shfl_xor(a20, 32, 64); a21 += __shfl_xor(a21, 32, 64);
    a30 += __shfl_xor(a30, 32, 64); a31 += __shfl_xor(a31, 32, 64);
    if (lh == 0) {
        float2* r2 = (float2*)(red + (w * TI) * GD + 2 * ld);
        r2[0 * GD / 2]           = make_float2(a00, a01);
        *(float2*)(red + (w * TI + 1) * GD + 2 * ld) = make_float2(a10, a11);
        *(float2*)(red + (w * TI + 2) * GD + 2 * ld) = make_float2(a20, a21);
        *(float2*)(red + (w * TI + 3) * GD + 2 * ld) = make_float2(a30, a31);
    }
    __syncthreads();

    if (tid < TI * GD) {
        const int r = tid >> 6, d = tid & 63;
        float o = 0.f;
        #pragma unroll
        for (int ww = 0; ww < 8; ++ww) o += red[(ww * TI + r) * GD + d];
        o = o + bias[d];
        out[((size_t)b * GN + i0 + r) * GD + d] = o;
    }
}

extern "C" void kernel_launch(void* const* d_in, const int* in_sizes, int n_in,
                              void* d_out, int out_size, void* d_ws, size_t ws_size,
                              hipStream_t stream) {
    const float* x    = (const float*)d_in[0];
    const int*   adj  = (const int*)d_in[1];
    const float* W    = (const float*)d_in[2];
    const float* a    = (const float*)d_in[3];
    const float* bias = (const float*)d_in[4];
    float* out = (float*)d_out;

    // ws layout: hbf ushort[GB*GN*GD] | s1 f32[GB*GN] | s2 f32[GB*GN]
    unsigned short* hbf = (unsigned short*)d_ws;
    float* s1f = (float*)((char*)d_ws + GB * GN * GD * sizeof(unsigned short));
    float* s2f = s1f + GB * GN;

    k_hidden<<<GB * GN / 4, 256, 0, stream>>>(x, W, a, hbf, s1f, s2f);
    k_attn<<<GB * GN / TI, 512, 0, stream>>>(adj, hbf, s1f, s2f, bias, out);
}